// Round 19
// baseline (116.778 us; speedup 1.0000x reference)
//
#include <hip/hip_runtime.h>

typedef unsigned long long ull;
typedef float f32x4 __attribute__((ext_vector_type(4)));

constexpr int N   = 500;
constexpr int HW  = 60800;    // 200*304
constexpr int NW  = 950;      // HW/64 (exact) real words per row
constexpr int NWP = 960;      // padded row stride = 15*64 (uniform unroll)
constexpr int NC  = 80;       // num classes
constexpr int GPR = 238;      // 256-px groups per row (237 full + 1 half)
constexpr int NTG = N * GPR;  // 119,000 pack groups
constexpr int PKB = 1023;     // pack blocks; +1 sort block = 1024 = resident cap
constexpr int IOUB = 256;     // blocks (of the y==0 row) that take IoU duty
constexpr int QPB = (HW / 4 + 255) / 256;   // 60 quad-chunks per instance
constexpr int CHUNK = 1024;   // decay LDS staging chunk (keeps LDS ~20 KB)

__device__ __forceinline__ void st_agent(int* p, int v) {
    __hip_atomic_store(p, v, __ATOMIC_RELAXED, __HIP_MEMORY_SCOPE_AGENT);
}
__device__ __forceinline__ int ld_agent(const int* p) {
    return __hip_atomic_load(p, __ATOMIC_RELAXED, __HIP_MEMORY_SCOPE_AGENT);
}

// ---------------------------------------------------------------------------
// Node 1. Block 0: pad zero-fill + stable score sort + per-class CSR + pair
// list + ticket/sentinel init.  Blocks 1..1023: float4-load + shfl_xor
// bit-pack (R17-proven).
__global__ void __launch_bounds__(512)
k_packsort(const float* __restrict__ mp, const int* __restrict__ labels,
           const float* __restrict__ scores,
           ull* __restrict__ packed, int* __restrict__ order_g,
           float* __restrict__ scoresS_g, int* __restrict__ labelsS_g,
           int2* __restrict__ pairList, int* __restrict__ counters,
           int* __restrict__ keepOrig_g) {
    const int t    = threadIdx.x;
    const int lane = t & 63;

    if (blockIdx.x != 0) {
        // ---- pack: one wave per 256-px group ----
        int wid = (blockIdx.x - 1) * 8 + (t >> 6);
        for (int g = wid; g < NTG; g += PKB * 8) {
            int row = g / GPR;                       // magic-mul
            int gr  = g - row * GPR;
            int px  = gr * 256 + lane * 4;           // pixel within row
            ull nib = 0;
            if (px < HW) {                           // tail group: lanes>=32 idle
                f32x4 v = *reinterpret_cast<const f32x4*>(mp + (size_t)row * HW + px);
                nib = (ull)((int)(v.x > 0.5f)
                          | ((int)(v.y > 0.5f) << 1)
                          | ((int)(v.z > 0.5f) << 2)
                          | ((int)(v.w > 0.5f) << 3));
            }
            ull word = nib << ((lane & 15) * 4);
            word |= __shfl_xor(word, 1, 64);         // OR-reduce within
            word |= __shfl_xor(word, 2, 64);         // 16-lane groups
            word |= __shfl_xor(word, 4, 64);
            word |= __shfl_xor(word, 8, 64);
            int wi = gr * 4 + (lane >> 4);           // word index in row
            if ((lane & 15) == 0 && wi < NW)
                packed[(size_t)row * NWP + wi] = word;
        }
        return;
    }

    // ---- block 0: pad zero-fill + init + sort + CSR + pairs ----
    __shared__ float sS[N];
    __shared__ int   orderS[N];
    __shared__ int   labS[N];
    __shared__ int   cnt[NC];
    __shared__ int   offs[NC + 1];
    __shared__ int   members[N];
    __shared__ int   pcnt;

    for (int u = t; u < N * (NWP - NW); u += 512) {      // zero rows' pad words
        int row = u / (NWP - NW), w = u - row * (NWP - NW);
        packed[(size_t)row * NWP + NW + w] = 0ULL;
    }
    if (t < N) keepOrig_g[t] = -1;     // spin sentinel for node 2
    if (t == 0) { counters[0] = 0; counters[1] = 0; pcnt = 0; }
    if (t < N) sS[t] = scores[t];
    if (t < NC) cnt[t] = 0;
    __syncthreads();
    if (t < N) {                       // stable descending rank sort
        float si = sS[t];
        int rank = 0;
        for (int j = 0; j < N; ++j) {
            float sj = sS[j];
            if (sj > si || (sj == si && j < t)) rank++;
        }
        orderS[rank] = t;
    }
    __syncthreads();
    int myLab = -1;
    if (t < N) {
        int o = orderS[t];
        order_g[t]   = o;
        scoresS_g[t] = sS[o];
        myLab = labels[o];
        labS[t] = myLab;
        labelsS_g[t] = myLab;
    }
    __syncthreads();
    if (t < N) atomicAdd(&cnt[myLab], 1);
    __syncthreads();
    if (t == 0) {
        int s = 0;
        for (int c = 0; c < NC; ++c) { offs[c] = s; s += cnt[c]; }
        offs[NC] = s;
    }
    __syncthreads();
    if (t < NC) cnt[t] = offs[t];      // insertion cursors
    __syncthreads();
    if (t < N) { int p = atomicAdd(&cnt[myLab], 1); members[p] = t; }
    __syncthreads();
    if (t < NC) {                      // enumerate same-class pairs (i<j)
        int b = offs[t], e = offs[t + 1];
        for (int a = b; a < e; ++a)
            for (int c2 = a + 1; c2 < e; ++c2) {
                int i = members[a], j = members[c2];
                int lo = min(i, j), hi = max(i, j);
                int p = atomicAdd(&pcnt, 1);
                pairList[p] = make_int2(lo, hi);
            }
    }
    __syncthreads();
    if (t == 0)  counters[2] = pcnt;   // pairCount
}

// ---------------------------------------------------------------------------
// Node 2. Grid (N, QPB): x = instance (y==0 row launches first). y==0 blocks
// take an arrival ticket; first IOUB run IoU stripes (R15-proven unrolled
// loop), drain vmcnt, second ticket elects the decay block (R14-proven LDS
// reduce) which publishes keepOrig. ALL blocks then value-spin on
// keepOrig[blockIdx.x] and write their gather chunk (R9-proven store path).
__global__ void __launch_bounds__(256)
k_ioudecaygather(const ull* __restrict__ packed, const int* __restrict__ order_g,
                 const float* __restrict__ scoresS_g, const int* __restrict__ labelsS_g,
                 const int2* __restrict__ pairList, int* __restrict__ counters,
                 int* __restrict__ iouC, int* __restrict__ keepOrig_g,
                 float* __restrict__ outScores, float* __restrict__ outLabels,
                 float* __restrict__ outKeep, f32x4* __restrict__ outMasks) {
    const int t    = threadIdx.x;
    const int lane = t & 63;
    const int wid  = t >> 6;
    __shared__ int sTick, sOrig;

    if (blockIdx.y == 0) {
        if (t == 0) sTick = __hip_atomic_fetch_add(counters, 1, __ATOMIC_RELAXED,
                                                   __HIP_MEMORY_SCOPE_AGENT);
        __syncthreads();
        if (sTick < IOUB) {
            // ---- IoU stripes (wave per pair; 4 waves/block) ----
            int np = counters[2];          // node-1 data (dispatch boundary)
            for (int p = sTick * 4 + wid; p < np; p += IOUB * 4) {
                int2 pr = pairList[p];
                const ull* A = packed + (size_t)order_g[pr.x] * NWP + lane;
                const ull* B = packed + (size_t)order_g[pr.y] * NWP + lane;
                ull acc = 0;  // inter | areaA<<21 | areaB<<42
#pragma unroll
                for (int k = 0; k < 15; ++k) {           // uniform, unrolled
                    ull a = A[k * 64], b = B[k * 64];
                    acc += (ull)__popcll(a & b)
                         + ((ull)__popcll(a) << 21)
                         + ((ull)__popcll(b) << 42);
                }
#pragma unroll
                for (int off = 32; off > 0; off >>= 1)
                    acc += __shfl_down(acc, off, 64);
                if (lane == 0) {
                    float inter = (float)(int)(acc & 0x1FFFFF);
                    float areaA = (float)(int)((acc >> 21) & 0x1FFFFF);
                    float areaB = (float)(int)((acc >> 42) & 0x1FFFFF);
                    st_agent(iouC + p,
                             __float_as_int(inter / (areaA + areaB - inter)));
                }
            }
            asm volatile("s_waitcnt vmcnt(0)" ::: "memory");   // stores at LLC
            __syncthreads();
            __shared__ int sLast;
            if (t == 0) sLast = __hip_atomic_fetch_add(counters + 1, 1,
                                    __ATOMIC_RELAXED, __HIP_MEMORY_SCOPE_AGENT);
            __syncthreads();
            if (sLast == IOUB - 1) {
                // ---- decay (elected): chunked stage + LDS-atomic reduce ----
                __shared__ int   compB[N];   // float bits, init 0.0f
                __shared__ int   coefB[N];   // float bits, init 1.0f
                __shared__ float sdec[N];
                __shared__ int2  pch[CHUNK];
                __shared__ float ich[CHUNK];
                int np2 = counters[2];
                for (int u = t; u < N; u += 256) { compB[u] = 0; coefB[u] = 0x3F800000; }
                __syncthreads();
                for (int base = 0; base < np2; base += CHUNK) {   // pass 1: comp
                    int n = min(np2 - base, CHUNK);
                    for (int u = t; u < n; u += 256) {
                        pch[u] = pairList[base + u];
                        ich[u] = __int_as_float(ld_agent(iouC + base + u));
                    }
                    __syncthreads();
                    for (int u = t; u < n; u += 256)
                        atomicMax(&compB[pch[u].y], __float_as_int(ich[u]));
                    __syncthreads();
                }
                for (int base = 0; base < np2; base += CHUNK) {   // pass 2: coef
                    int n = min(np2 - base, CHUNK);
                    for (int u = t; u < n; u += 256) {
                        pch[u] = pairList[base + u];
                        ich[u] = __int_as_float(ld_agent(iouC + base + u));
                    }
                    __syncthreads();
                    for (int u = t; u < n; u += 256) {
                        float d  = ich[u];
                        float ci = __int_as_float(compB[pch[u].x]);
                        float r  = expf(-2.f * d * d) / expf(-2.f * ci * ci);
                        atomicMin(&coefB[pch[u].y], __float_as_int(r));
                    }
                    __syncthreads();
                }
                for (int j = t; j < N; j += 256)
                    sdec[j] = scoresS_g[j] * __int_as_float(coefB[j]);
                __syncthreads();
                for (int j = t; j < N; j += 256) {   // stable descending rank
                    float sj = sdec[j];
                    int rank = 0;
                    for (int i = 0; i < N; ++i) {
                        float si = sdec[i];
                        if (si > sj || (si == sj && i < j)) rank++;
                    }
                    int o = order_g[j];
                    outScores[rank] = sj;
                    outLabels[rank] = (float)labelsS_g[j];
                    outKeep[rank]   = (float)o;
                    st_agent(keepOrig_g + rank, o);   // releases all spinners
                }
            }
        }
    }

    // ---- gather: every block, one 1024-px chunk of instance blockIdx.x ----
    int k = blockIdx.x;
    if (t == 0) {
        int v;
        while ((v = ld_agent(keepOrig_g + k)) < 0) __builtin_amdgcn_s_sleep(8);
        sOrig = v;
    }
    __syncthreads();
    int q = blockIdx.y * 256 + t;                    // quad within instance
    if (q >= HW / 4) return;
    ull w  = packed[(size_t)sOrig * NWP + (q >> 4)];
    int sh = (q & 15) * 4;
    f32x4 r;
    r.x = (float)((w >> (sh    )) & 1ULL);
    r.y = (float)((w >> (sh + 1)) & 1ULL);
    r.z = (float)((w >> (sh + 2)) & 1ULL);
    r.w = (float)((w >> (sh + 3)) & 1ULL);
    outMasks[(size_t)k * (HW / 4) + q] = r;
}

// ---------------------------------------------------------------------------
extern "C" void kernel_launch(void* const* d_in, const int* in_sizes, int n_in,
                              void* d_out, int out_size, void* d_ws, size_t ws_size,
                              hipStream_t stream) {
    const float* mask_preds = (const float*)d_in[0];
    const int*   labels     = (const int*)d_in[1];
    const float* scores     = (const float*)d_in[2];

    float*  o         = (float*)d_out;
    float*  outScores = o;
    float*  outLabels = o + N;
    f32x4*  outMasks  = (f32x4*)(o + 2 * N);
    float*  outKeep   = o + 2 * N + (size_t)N * HW;

    // workspace carve-up (16B-aligned chunks; ~5.4 MB total)
    char* w = (char*)d_ws;
    ull*   packed     = (ull*)w;   w += (size_t)N * NWP * 8;           // 3,840,000
    int*   order_g    = (int*)w;   w += N * 4;
    float* scoresS_g  = (float*)w; w += N * 4;
    int*   labelsS_g  = (int*)w;   w += N * 4;
    int*   keepOrig_g = (int*)w;   w += N * 4;
    int*   counters   = (int*)w;   w += 128;   // ticket1, ticket2, pairCount
    int*   iouC       = (int*)w;   w += (size_t)(N * (N - 1) / 2) * 4; // 499,000
    int2*  pairList   = (int2*)w;  /* N*(N-1)/2 * 8 = 998,000 */

    hipLaunchKernelGGL(k_packsort, dim3(PKB + 1), dim3(512), 0, stream,
                       mask_preds, labels, scores, packed, order_g,
                       scoresS_g, labelsS_g, pairList, counters, keepOrig_g);
    hipLaunchKernelGGL(k_ioudecaygather, dim3(N, QPB), dim3(256), 0, stream,
                       packed, order_g, scoresS_g, labelsS_g,
                       pairList, counters, iouC, keepOrig_g,
                       outScores, outLabels, outKeep, outMasks);
}

// Round 20
// 110.207 us; speedup vs baseline: 1.0596x; 1.0596x over previous
//
#include <hip/hip_runtime.h>

typedef unsigned long long ull;
typedef float f32x4 __attribute__((ext_vector_type(4)));

constexpr int N    = 500;
constexpr int HW   = 60800;   // 200*304
constexpr int NW   = 950;     // HW/64 (exact) real words per row
constexpr int NWP  = 960;     // padded row stride = 15*64
constexpr int NC   = 80;      // num classes
constexpr int GPR  = 238;     // 256-px groups per row (237 full + 1 half)
constexpr int NTG  = N * GPR; // 119,000 pack groups
constexpr int PKB  = 1023;    // pack blocks; +1 sort block = 1024 = resident cap
constexpr int NTILE = NWP / 64;             // 15 word-tiles per row
constexpr int QPB  = (HW / 4 + 255) / 256;  // 60 quad-chunks per instance
constexpr int MAXM = 64;      // max members per class the LDS buffer holds
constexpr int CHUNK = 3072;   // decay staging chunk (pairs)

// ---------------------------------------------------------------------------
// Node 1. Block 0: pad zero-fill + stable score sort + per-class CSR +
// per-class CONTIGUOUS pair list + accumulator zeroing.  Blocks 1..1023:
// float4-load + shfl_xor bit-pack (R17-proven).
__global__ void __launch_bounds__(512)
k_packsort(const float* __restrict__ mp, const int* __restrict__ labels,
           const float* __restrict__ scores,
           ull* __restrict__ packed, int* __restrict__ order_g,
           float* __restrict__ scoresS_g, int* __restrict__ labelsS_g,
           int* __restrict__ offs_g, int* __restrict__ members_g,
           int* __restrict__ pairBase_g, int2* __restrict__ pairList,
           int* __restrict__ interAcc, int* __restrict__ areaAcc) {
    const int t    = threadIdx.x;
    const int lane = t & 63;

    if (blockIdx.x != 0) {
        // ---- pack: one wave per 256-px group ----
        int wid = (blockIdx.x - 1) * 8 + (t >> 6);
        for (int g = wid; g < NTG; g += PKB * 8) {
            int row = g / GPR;                       // magic-mul
            int gr  = g - row * GPR;
            int px  = gr * 256 + lane * 4;           // pixel within row
            ull nib = 0;
            if (px < HW) {                           // tail group: lanes>=32 idle
                f32x4 v = *reinterpret_cast<const f32x4*>(mp + (size_t)row * HW + px);
                nib = (ull)((int)(v.x > 0.5f)
                          | ((int)(v.y > 0.5f) << 1)
                          | ((int)(v.z > 0.5f) << 2)
                          | ((int)(v.w > 0.5f) << 3));
            }
            ull word = nib << ((lane & 15) * 4);
            word |= __shfl_xor(word, 1, 64);         // OR-reduce within
            word |= __shfl_xor(word, 2, 64);         // 16-lane groups
            word |= __shfl_xor(word, 4, 64);
            word |= __shfl_xor(word, 8, 64);
            int wi = gr * 4 + (lane >> 4);           // word index in row
            if ((lane & 15) == 0 && wi < NW)
                packed[(size_t)row * NWP + wi] = word;
        }
        return;
    }

    // ---- block 0: pad zero-fill + init + sort + CSR + pairs + zeroing ----
    __shared__ float sS[N];
    __shared__ int   orderS[N];
    __shared__ int   labS[N];
    __shared__ int   cnt[NC];
    __shared__ int   offs[NC + 1];
    __shared__ int   members[N];
    __shared__ int   pairBase[NC + 1];

    for (int u = t; u < N * (NWP - NW); u += 512) {      // zero rows' pad words
        int row = u / (NWP - NW), w = u - row * (NWP - NW);
        packed[(size_t)row * NWP + NW + w] = 0ULL;
    }
    if (t < N) sS[t] = scores[t];
    if (t < NC) cnt[t] = 0;
    __syncthreads();
    if (t < N) {                       // stable descending rank sort
        float si = sS[t];
        int rank = 0;
        for (int j = 0; j < N; ++j) {
            float sj = sS[j];
            if (sj > si || (sj == si && j < t)) rank++;
        }
        orderS[rank] = t;
    }
    __syncthreads();
    int myLab = -1;
    if (t < N) {
        int o = orderS[t];
        order_g[t]   = o;
        scoresS_g[t] = sS[o];
        myLab = labels[o];
        labS[t] = myLab;
        labelsS_g[t] = myLab;
    }
    __syncthreads();
    if (t < N) atomicAdd(&cnt[myLab], 1);
    __syncthreads();
    if (t == 0) {
        int s = 0, pb = 0;
        for (int c = 0; c < NC; ++c) {
            offs[c] = s;  pairBase[c] = pb;
            int mc = cnt[c];
            s += mc;  pb += mc * (mc - 1) / 2;
        }
        offs[NC] = s;  pairBase[NC] = pb;
    }
    __syncthreads();
    if (t < NC) cnt[t] = offs[t];      // insertion cursors
    __syncthreads();
    if (t < N) { int p = atomicAdd(&cnt[myLab], 1); members[p] = t; }
    __syncthreads();
    if (t < NC) {                      // per-class pairs, slot-lexicographic
        int b = offs[t], m = offs[t + 1] - offs[t];
        int p = pairBase[t];
        for (int a = 0; a < m; ++a)
            for (int b2 = a + 1; b2 < m; ++b2, ++p) {
                int i = members[b + a], j = members[b + b2];
                pairList[p] = make_int2(min(i, j), max(i, j));
            }
    }
    __syncthreads();
    int np = pairBase[NC];
    for (int u = t; u < np; u += 512) interAcc[u] = 0;
    if (t < N)   areaAcc[t] = 0;
    if (t < N)   members_g[t] = members[t];
    if (t <= NC) { offs_g[t] = offs[t]; pairBase_g[t] = pairBase[t]; }
}

// ---------------------------------------------------------------------------
// Node 2. Grid (NC, NTILE), 1 wave/block: load the class's member row
// segments for this word-tile into LDS ONCE (16-way unrolled predicated
// loads), then accumulate pair intersections + member areas via atomicAdd.
// Every byte of `packed` is read exactly once across the whole grid.
__global__ void __launch_bounds__(64)
k_iouacc(const ull* __restrict__ packed, const int* __restrict__ order_g,
         const int* __restrict__ offs_g, const int* __restrict__ members_g,
         const int* __restrict__ pairBase_g,
         int* __restrict__ interAcc, int* __restrict__ areaAcc) {
    __shared__ ull rows[MAXM * 64];
    __shared__ int oArr[MAXM];
    __shared__ int memArr[MAXM];
    const int lane = threadIdx.x;
    const int c    = blockIdx.x;
    const int tile = blockIdx.y;

    int b = offs_g[c], m = offs_g[c + 1] - b;
    if (m < 2) return;                       // no pairs -> nothing to do
    if (lane < m) {
        int j = members_g[b + lane];
        memArr[lane] = j;
        oArr[lane]   = order_g[j];
    }
    // (single wave: LDS writes above are ordered before reads below)
    for (int base = 0; base < m; base += 16) {
#pragma unroll
        for (int r = 0; r < 16; ++r) {       // 16 loads in flight at once
            int rr = base + r;
            ull v = 0;
            if (rr < m)
                v = packed[(size_t)oArr[rr] * NWP + tile * 64 + lane];
            rows[rr * 64 + lane] = v;
        }
    }
    for (int r = 0; r < m; ++r) {            // member areas (this tile's part)
        int cnt = (int)__popcll(rows[r * 64 + lane]);
#pragma unroll
        for (int off = 32; off > 0; off >>= 1) cnt += __shfl_down(cnt, off, 64);
        if (lane == 0) atomicAdd(areaAcc + memArr[r], cnt);
    }
    int p = pairBase_g[c];                   // pair intersections (this tile)
    for (int a = 0; a < m; ++a) {
        ull va = rows[a * 64 + lane];
        for (int b2 = a + 1; b2 < m; ++b2, ++p) {
            int cnt = (int)__popcll(va & rows[b2 * 64 + lane]);
#pragma unroll
            for (int off = 32; off > 0; off >>= 1) cnt += __shfl_down(cnt, off, 64);
            if (lane == 0) atomicAdd(interAcc + p, cnt);
        }
    }
}

// ---------------------------------------------------------------------------
// Node 3. Single block: compute IoU from accumulators (exact ints), comp via
// LDS atomicMax, coef via LDS atomicMin (R14-proven order-free math), decayed
// scores, stable rank sort, outputs. All plain loads (dispatch boundary).
__global__ void __launch_bounds__(512)
k_decay(const float* __restrict__ scoresS_g, const int* __restrict__ labelsS_g,
        const int* __restrict__ order_g, const int* __restrict__ pairBase_g,
        const int2* __restrict__ pairList, const int* __restrict__ interAcc,
        const int* __restrict__ areaAcc, int* __restrict__ keepOrig_g,
        float* __restrict__ outScores, float* __restrict__ outLabels,
        float* __restrict__ outKeep) {
    const int t = threadIdx.x;
    __shared__ float areaS[N];
    __shared__ int   compB[N];     // float bits of comp[j]  (init 0.0f)
    __shared__ int   coefB[N];     // float bits of coef[j]  (init 1.0f)
    __shared__ float sdec[N];
    __shared__ int2  pch[CHUNK];
    __shared__ float ich[CHUNK];

    int np = pairBase_g[NC];
    if (t < N) {
        areaS[t] = (float)areaAcc[t];
        compB[t] = 0;
        coefB[t] = 0x3F800000;
    }
    __syncthreads();
    for (int base = 0; base < np; base += CHUNK) {   // pass 1: comp = max iou
        int n = min(np - base, CHUNK);
        for (int u = t; u < n; u += 512) {
            int2 pr = pairList[base + u];
            float inter = (float)interAcc[base + u];
            pch[u] = pr;
            ich[u] = inter / (areaS[pr.x] + areaS[pr.y] - inter);
        }
        __syncthreads();
        for (int u = t; u < n; u += 512)
            atomicMax(&compB[pch[u].y], __float_as_int(ich[u]));
        __syncthreads();
    }
    for (int base = 0; base < np; base += CHUNK) {   // pass 2: coef = min ratio
        int n = min(np - base, CHUNK);
        for (int u = t; u < n; u += 512) {
            int2 pr = pairList[base + u];
            float inter = (float)interAcc[base + u];
            pch[u] = pr;
            ich[u] = inter / (areaS[pr.x] + areaS[pr.y] - inter);
        }
        __syncthreads();
        for (int u = t; u < n; u += 512) {
            float d  = ich[u];
            float ci = __int_as_float(compB[pch[u].x]);
            float r  = expf(-2.f * d * d) / expf(-2.f * ci * ci);  // mirror np
            atomicMin(&coefB[pch[u].y], __float_as_int(r));
        }
        __syncthreads();
    }
    if (t < N) sdec[t] = scoresS_g[t] * __int_as_float(coefB[t]);
    __syncthreads();
    if (t < N) {                        // stable descending rank on decayed scores
        float sj = sdec[t];
        int rank = 0;
        for (int i = 0; i < N; ++i) {
            float si = sdec[i];
            if (si > sj || (si == sj && i < t)) rank++;
        }
        int o = order_g[t];
        outScores[rank]  = sj;
        outLabels[rank]  = (float)labelsS_g[t];
        outKeep[rank]    = (float)o;
        keepOrig_g[rank] = o;
    }
}

// ---------------------------------------------------------------------------
// Node 4. Expand kept masks to float output. 2D grid (R9-proven best);
// plain coalesced f32x4 stores; padded row stride.
__global__ void k_gather(const ull* __restrict__ packed, const int* __restrict__ keepOrig,
                         f32x4* __restrict__ outMasks) {
    int q = blockIdx.x * blockDim.x + threadIdx.x;   // quad within instance
    if (q >= HW / 4) return;
    int k    = blockIdx.y;
    int orig = keepOrig[k];                          // uniform -> scalar load
    ull w  = packed[(size_t)orig * NWP + (q >> 4)];  // pix = q*4; word = pix>>6
    int sh = (q & 15) * 4;
    f32x4 r;
    r.x = (float)((w >> (sh    )) & 1ULL);
    r.y = (float)((w >> (sh + 1)) & 1ULL);
    r.z = (float)((w >> (sh + 2)) & 1ULL);
    r.w = (float)((w >> (sh + 3)) & 1ULL);
    outMasks[(size_t)k * (HW / 4) + q] = r;
}

// ---------------------------------------------------------------------------
extern "C" void kernel_launch(void* const* d_in, const int* in_sizes, int n_in,
                              void* d_out, int out_size, void* d_ws, size_t ws_size,
                              hipStream_t stream) {
    const float* mask_preds = (const float*)d_in[0];
    const int*   labels     = (const int*)d_in[1];
    const float* scores     = (const float*)d_in[2];

    float*  o         = (float*)d_out;
    float*  outScores = o;
    float*  outLabels = o + N;
    f32x4*  outMasks  = (f32x4*)(o + 2 * N);
    float*  outKeep   = o + 2 * N + (size_t)N * HW;

    // workspace carve-up (16B-aligned chunks; ~5.4 MB total)
    char* w = (char*)d_ws;
    ull*   packed     = (ull*)w;   w += (size_t)N * NWP * 8;           // 3,840,000
    int*   order_g    = (int*)w;   w += N * 4;
    float* scoresS_g  = (float*)w; w += N * 4;
    int*   labelsS_g  = (int*)w;   w += N * 4;
    int*   offs_g     = (int*)w;   w += (NC + 4) * 4;
    int*   members_g  = (int*)w;   w += N * 4;
    int*   pairBase_g = (int*)w;   w += (NC + 4) * 4;
    int*   keepOrig_g = (int*)w;   w += N * 4;
    int*   areaAcc    = (int*)w;   w += N * 4;
    int*   interAcc   = (int*)w;   w += (size_t)(N * (N - 1) / 2) * 4; // 499,000
    int2*  pairList   = (int2*)w;  /* N*(N-1)/2 * 8 = 998,000 */

    hipLaunchKernelGGL(k_packsort, dim3(PKB + 1), dim3(512), 0, stream,
                       mask_preds, labels, scores, packed, order_g,
                       scoresS_g, labelsS_g, offs_g, members_g,
                       pairBase_g, pairList, interAcc, areaAcc);
    hipLaunchKernelGGL(k_iouacc, dim3(NC, NTILE), dim3(64), 0, stream,
                       packed, order_g, offs_g, members_g, pairBase_g,
                       interAcc, areaAcc);
    hipLaunchKernelGGL(k_decay, dim3(1), dim3(512), 0, stream,
                       scoresS_g, labelsS_g, order_g, pairBase_g, pairList,
                       interAcc, areaAcc, keepOrig_g,
                       outScores, outLabels, outKeep);
    hipLaunchKernelGGL(k_gather, dim3(QPB, N), dim3(256), 0, stream,
                       packed, keepOrig_g, outMasks);
}

// Round 21
// 76.442 us; speedup vs baseline: 1.5277x; 1.4417x over previous
//
#include <hip/hip_runtime.h>

typedef unsigned long long ull;
typedef float f32x4 __attribute__((ext_vector_type(4)));

constexpr int N   = 500;
constexpr int HW  = 60800;    // 200*304
constexpr int NW  = 950;      // HW/64 (exact) real words per row
constexpr int NWP = 960;      // padded row stride = 15*64 (uniform unroll)
constexpr int NC  = 80;       // num classes
constexpr int TPR = 475;      // 128-px tiles per row (60800/128, exact)
constexpr int NT2 = N * TPR;  // 237,500 pack tiles
constexpr int PB  = 1024;     // pack blocks (block 0 does the sort instead)
constexpr int IOUB = 256;     // IoU blocks in node 2
constexpr int QPB = (HW / 4 + 255) / 256;   // 60 blocks of quads per instance
constexpr int CHUNK = 3072;   // decay LDS staging chunk (pairs)

// ---------------------------------------------------------------------------
// Node 1. Block 0: stable score sort + per-class CSR + pair list + row-pad
// zero-fill + ticket init.  Blocks 1..PB: binarize + bit-pack mask_preds
// (128-px tiles -> ulonglong2 at padded stride).
__global__ void __launch_bounds__(512)
k_packsort(const float* __restrict__ mp, const int* __restrict__ labels,
           const float* __restrict__ scores,
           ull* __restrict__ packed, int* __restrict__ order_g,
           float* __restrict__ scoresS_g, int* __restrict__ labelsS_g,
           int2* __restrict__ pairList, int* __restrict__ counters) {
    const int t    = threadIdx.x;
    const int lane = t & 63;

    if (blockIdx.x != 0) {
        // ---- pack ----
        int wid = (blockIdx.x - 1) * 8 + (t >> 6);
        for (int tile = wid; tile < NT2; tile += PB * 8) {
            size_t base = (size_t)tile * 128;            // pixel base (exact)
            float v0 = mp[base +  0 + lane];
            float v1 = mp[base + 64 + lane];
            ull b0 = __ballot(v0 > 0.5f);
            ull b1 = __ballot(v1 > 0.5f);
            if (lane == 0) {
                int row = tile / TPR;                    // magic-mul
                int tr  = tile - row * TPR;
                ulonglong2 w2; w2.x = b0; w2.y = b1;
                *(ulonglong2*)(packed + (size_t)row * NWP + tr * 2) = w2;
            }
        }
        return;
    }

    // ---- block 0: pad zero-fill + init + sort + CSR + pairs ----
    __shared__ float sS[N];
    __shared__ int   orderS[N];
    __shared__ int   labS[N];
    __shared__ int   cnt[NC];
    __shared__ int   offs[NC + 1];
    __shared__ int   members[N];
    __shared__ int   pcnt;

    for (int u = t; u < N * (NWP - NW); u += 512) {      // zero rows' pad words
        int row = u / (NWP - NW), w = u - row * (NWP - NW);
        packed[(size_t)row * NWP + NW + w] = 0ULL;
    }
    if (t == 0) { counters[0] = 0; pcnt = 0; }   // done-ticket for node 2
    if (t < N) sS[t] = scores[t];
    if (t < NC) cnt[t] = 0;
    __syncthreads();
    if (t < N) {                       // stable descending rank sort
        float si = sS[t];
        int rank = 0;
        for (int j = 0; j < N; ++j) {
            float sj = sS[j];
            if (sj > si || (sj == si && j < t)) rank++;
        }
        orderS[rank] = t;
    }
    __syncthreads();
    int myLab = -1;
    if (t < N) {
        int o = orderS[t];
        order_g[t]   = o;
        scoresS_g[t] = sS[o];
        myLab = labels[o];
        labS[t] = myLab;
        labelsS_g[t] = myLab;
    }
    __syncthreads();
    if (t < N) atomicAdd(&cnt[myLab], 1);
    __syncthreads();
    if (t == 0) {
        int s = 0;
        for (int c = 0; c < NC; ++c) { offs[c] = s; s += cnt[c]; }
        offs[NC] = s;
    }
    __syncthreads();
    if (t < NC) cnt[t] = offs[t];      // insertion cursors
    __syncthreads();
    if (t < N) { int p = atomicAdd(&cnt[myLab], 1); members[p] = t; }
    __syncthreads();
    if (t < NC) {                      // enumerate same-class pairs (i<j)
        int b = offs[t], e = offs[t + 1];
        for (int a = b; a < e; ++a)
            for (int c2 = a + 1; c2 < e; ++c2) {
                int i = members[a], j = members[c2];
                int lo = min(i, j), hi = max(i, j);
                int p = atomicAdd(&pcnt, 1);
                pairList[p] = make_int2(lo, hi);
            }
    }
    __syncthreads();
    if (t == 0)  counters[1] = pcnt;   // pairCount
}

// ---------------------------------------------------------------------------
// Node 2. 256 blocks: IoU per pair with fully-unrolled 15-iteration word loop
// (uniform via 960-word padded stride). Then vmcnt drain + done-ticket elects
// the last block for the LDS-reduce decay + final sort.
__global__ void __launch_bounds__(512)
k_ioudecay(const ull* __restrict__ packed, const int* __restrict__ order_g,
           const float* __restrict__ scoresS_g, const int* __restrict__ labelsS_g,
           const int2* __restrict__ pairList, int* __restrict__ counters,
           int* __restrict__ iouC, int* __restrict__ keepOrig_g,
           float* __restrict__ outScores, float* __restrict__ outLabels,
           float* __restrict__ outKeep) {
    const int t    = threadIdx.x;
    const int lane = t & 63;
    __shared__ int sLast;

    // ---- IoU stripes (wave per pair) ----
    int np = counters[1];              // node-1 data (dispatch boundary)
    for (int p = (int)blockIdx.x * 8 + (t >> 6); p < np; p += IOUB * 8) {
        int2 pr = pairList[p];
        const ull* A = packed + (size_t)order_g[pr.x] * NWP + lane;
        const ull* B = packed + (size_t)order_g[pr.y] * NWP + lane;
        ull acc = 0;  // inter | areaA<<21 | areaB<<42  (fields < 2^17)
#pragma unroll
        for (int k = 0; k < 15; ++k) {                   // uniform, unrolled
            ull a = A[k * 64], b = B[k * 64];
            acc += (ull)__popcll(a & b)
                 + ((ull)__popcll(a) << 21)
                 + ((ull)__popcll(b) << 42);
        }
#pragma unroll
        for (int off = 32; off > 0; off >>= 1) acc += __shfl_down(acc, off, 64);
        if (lane == 0) {
            float inter = (float)(int)(acc & 0x1FFFFF);
            float areaA = (float)(int)((acc >> 21) & 0x1FFFFF);
            float areaB = (float)(int)((acc >> 42) & 0x1FFFFF);
            float uni   = areaA + areaB - inter;    // exact small ints
            __hip_atomic_store(iouC + p, __float_as_int(inter / uni),
                               __ATOMIC_RELAXED, __HIP_MEMORY_SCOPE_AGENT);
        }
    }
    asm volatile("s_waitcnt vmcnt(0)" ::: "memory");   // stores at LLC
    __syncthreads();                                    // all waves drained
    if (t == 0) sLast = __hip_atomic_fetch_add(counters, 1, __ATOMIC_RELAXED,
                                               __HIP_MEMORY_SCOPE_AGENT);
    __syncthreads();
    if (sLast != IOUB - 1) return;

    // ---- decay (elected block): parallel stage + LDS-atomic reduce ----
    __shared__ int   labS[N];
    __shared__ int   compB[N];     // float bits of comp[j]  (init 0.0f)
    __shared__ int   coefB[N];     // float bits of coef[j]  (init 1.0f)
    __shared__ float sdec[N];
    __shared__ int2  pch[CHUNK];
    __shared__ float ich[CHUNK];

    if (t < N) {
        labS[t]  = labelsS_g[t];
        compB[t] = 0;              // 0.0f
        coefB[t] = 0x3F800000;     // 1.0f
    }
    __syncthreads();
    // pass 1: comp[j] = max over pairs (i,j) of iou   (exact, order-free)
    for (int base = 0; base < np; base += CHUNK) {
        int n = min(np - base, CHUNK);
        for (int u = t; u < n; u += 512) {
            pch[u] = pairList[base + u];
            ich[u] = __int_as_float(__hip_atomic_load(
                iouC + base + u, __ATOMIC_RELAXED, __HIP_MEMORY_SCOPE_AGENT));
        }
        __syncthreads();
        for (int u = t; u < n; u += 512)
            atomicMax(&compB[pch[u].y], __float_as_int(ich[u]));
        __syncthreads();
    }
    // pass 2: coef[j] = min over pairs (i,j) of exp(-2d^2)/exp(-2 comp[i]^2)
    for (int base = 0; base < np; base += CHUNK) {
        int n = min(np - base, CHUNK);
        for (int u = t; u < n; u += 512) {
            pch[u] = pairList[base + u];
            ich[u] = __int_as_float(__hip_atomic_load(
                iouC + base + u, __ATOMIC_RELAXED, __HIP_MEMORY_SCOPE_AGENT));
        }
        __syncthreads();
        for (int u = t; u < n; u += 512) {
            float d  = ich[u];
            float ci = __int_as_float(compB[pch[u].x]);
            float r  = expf(-2.f * d * d) / expf(-2.f * ci * ci);  // mirror np
            atomicMin(&coefB[pch[u].y], __float_as_int(r));
        }
        __syncthreads();
    }
    if (t < N) sdec[t] = scoresS_g[t] * __int_as_float(coefB[t]);
    __syncthreads();
    if (t < N) {                        // stable descending rank on decayed scores
        float sj = sdec[t];
        int rank = 0;
        for (int i = 0; i < N; ++i) {
            float si = sdec[i];
            if (si > sj || (si == sj && i < t)) rank++;
        }
        int o = order_g[t];
        outScores[rank]  = sj;
        outLabels[rank]  = (float)labS[t];
        outKeep[rank]    = (float)o;
        keepOrig_g[rank] = o;
    }
}

// ---------------------------------------------------------------------------
// Node 3. Expand kept masks to float output. 2D grid (R9-proven best);
// plain coalesced f32x4 stores; padded row stride.
__global__ void k_gather(const ull* __restrict__ packed, const int* __restrict__ keepOrig,
                         f32x4* __restrict__ outMasks) {
    int q = blockIdx.x * blockDim.x + threadIdx.x;   // quad within instance
    if (q >= HW / 4) return;
    int k    = blockIdx.y;
    int orig = keepOrig[k];                          // uniform -> scalar load
    ull w  = packed[(size_t)orig * NWP + (q >> 4)];  // pix = q*4; word = pix>>6
    int sh = (q & 15) * 4;
    f32x4 r;
    r.x = (float)((w >> (sh    )) & 1ULL);
    r.y = (float)((w >> (sh + 1)) & 1ULL);
    r.z = (float)((w >> (sh + 2)) & 1ULL);
    r.w = (float)((w >> (sh + 3)) & 1ULL);
    outMasks[(size_t)k * (HW / 4) + q] = r;
}

// ---------------------------------------------------------------------------
extern "C" void kernel_launch(void* const* d_in, const int* in_sizes, int n_in,
                              void* d_out, int out_size, void* d_ws, size_t ws_size,
                              hipStream_t stream) {
    const float* mask_preds = (const float*)d_in[0];
    const int*   labels     = (const int*)d_in[1];
    const float* scores     = (const float*)d_in[2];

    float*  o         = (float*)d_out;
    float*  outScores = o;
    float*  outLabels = o + N;
    f32x4*  outMasks  = (f32x4*)(o + 2 * N);
    float*  outKeep   = o + 2 * N + (size_t)N * HW;

    // workspace carve-up (16B-aligned chunks; ~5.4 MB total)
    char* w = (char*)d_ws;
    ull*   packed     = (ull*)w;   w += (size_t)N * NWP * 8;           // 3,840,000
    int*   order_g    = (int*)w;   w += N * 4;
    float* scoresS_g  = (float*)w; w += N * 4;
    int*   labelsS_g  = (int*)w;   w += N * 4;
    int*   keepOrig_g = (int*)w;   w += N * 4;
    int*   counters   = (int*)w;   w += 128;   // done-ticket, pairCount
    int*   iouC       = (int*)w;   w += (size_t)(N * (N - 1) / 2) * 4; // 499,000
    int2*  pairList   = (int2*)w;  /* N*(N-1)/2 * 8 = 998,000 */

    hipLaunchKernelGGL(k_packsort, dim3(PB + 1), dim3(512), 0, stream,
                       mask_preds, labels, scores, packed, order_g,
                       scoresS_g, labelsS_g, pairList, counters);
    hipLaunchKernelGGL(k_ioudecay, dim3(IOUB), dim3(512), 0, stream,
                       packed, order_g, scoresS_g, labelsS_g,
                       pairList, counters, iouC, keepOrig_g,
                       outScores, outLabels, outKeep);
    hipLaunchKernelGGL(k_gather, dim3(QPB, N), dim3(256), 0, stream,
                       packed, keepOrig_g, outMasks);
}

// Round 22
// 76.371 us; speedup vs baseline: 1.5291x; 1.0009x over previous
//
#include <hip/hip_runtime.h>

typedef unsigned long long ull;
typedef float f32x4 __attribute__((ext_vector_type(4)));

constexpr int N   = 500;
constexpr int HW  = 60800;    // 200*304
constexpr int NW  = 950;      // HW/64 (exact) real words per row
constexpr int NWP = 960;      // padded row stride = 15*64 (uniform unroll)
constexpr int NC  = 80;       // num classes
constexpr int TPR = 475;      // 128-px tiles per row (60800/128, exact)
constexpr int NT2 = N * TPR;  // 237,500 pack tiles
constexpr int PB  = 1024;     // pack blocks (block 0 does the sort instead)
constexpr int IOUB = 256;     // IoU blocks in node 2
constexpr int QPB = (HW / 4 + 255) / 256;   // 60 blocks of quads per instance
constexpr int CHUNK = 3072;   // decay LDS staging chunk (pairs)

// ---------------------------------------------------------------------------
// Node 1. Block 0: stable score sort + per-class CSR + PER-CLASS CONTIGUOUS
// pair list (consecutive pairs share rows -> L1/L2 reuse in node 2) + row-pad
// zero-fill + ticket init.  Blocks 1..PB: binarize + bit-pack mask_preds
// (128-px tiles -> ulonglong2 at padded stride).
__global__ void __launch_bounds__(512)
k_packsort(const float* __restrict__ mp, const int* __restrict__ labels,
           const float* __restrict__ scores,
           ull* __restrict__ packed, int* __restrict__ order_g,
           float* __restrict__ scoresS_g, int* __restrict__ labelsS_g,
           int2* __restrict__ pairList, int* __restrict__ counters) {
    const int t    = threadIdx.x;
    const int lane = t & 63;

    if (blockIdx.x != 0) {
        // ---- pack ----
        int wid = (blockIdx.x - 1) * 8 + (t >> 6);
        for (int tile = wid; tile < NT2; tile += PB * 8) {
            size_t base = (size_t)tile * 128;            // pixel base (exact)
            float v0 = mp[base +  0 + lane];
            float v1 = mp[base + 64 + lane];
            ull b0 = __ballot(v0 > 0.5f);
            ull b1 = __ballot(v1 > 0.5f);
            if (lane == 0) {
                int row = tile / TPR;                    // magic-mul
                int tr  = tile - row * TPR;
                ulonglong2 w2; w2.x = b0; w2.y = b1;
                *(ulonglong2*)(packed + (size_t)row * NWP + tr * 2) = w2;
            }
        }
        return;
    }

    // ---- block 0: pad zero-fill + init + sort + CSR + contiguous pairs ----
    __shared__ float sS[N];
    __shared__ int   orderS[N];
    __shared__ int   labS[N];
    __shared__ int   cnt[NC];
    __shared__ int   offs[NC + 1];
    __shared__ int   members[N];
    __shared__ int   pairBase[NC + 1];

    for (int u = t; u < N * (NWP - NW); u += 512) {      // zero rows' pad words
        int row = u / (NWP - NW), w = u - row * (NWP - NW);
        packed[(size_t)row * NWP + NW + w] = 0ULL;
    }
    if (t == 0) counters[0] = 0;       // done-ticket for node 2
    if (t < N) sS[t] = scores[t];
    if (t < NC) cnt[t] = 0;
    __syncthreads();
    if (t < N) {                       // stable descending rank sort
        float si = sS[t];
        int rank = 0;
        for (int j = 0; j < N; ++j) {
            float sj = sS[j];
            if (sj > si || (sj == si && j < t)) rank++;
        }
        orderS[rank] = t;
    }
    __syncthreads();
    int myLab = -1;
    if (t < N) {
        int o = orderS[t];
        order_g[t]   = o;
        scoresS_g[t] = sS[o];
        myLab = labels[o];
        labS[t] = myLab;
        labelsS_g[t] = myLab;
    }
    __syncthreads();
    if (t < N) atomicAdd(&cnt[myLab], 1);
    __syncthreads();
    if (t == 0) {
        int s = 0, pb = 0;
        for (int c = 0; c < NC; ++c) {
            offs[c] = s;  pairBase[c] = pb;
            int mc = cnt[c];
            s += mc;  pb += mc * (mc - 1) / 2;
        }
        offs[NC] = s;  pairBase[NC] = pb;
    }
    __syncthreads();
    if (t < NC) cnt[t] = offs[t];      // insertion cursors
    __syncthreads();
    if (t < N) { int p = atomicAdd(&cnt[myLab], 1); members[p] = t; }
    __syncthreads();
    if (t < NC) {                      // per-class pairs, slot-lexicographic:
        int b = offs[t], m = offs[t + 1] - offs[t];      // consecutive pairs
        int p = pairBase[t];                             // share row a
        for (int a = 0; a < m; ++a)
            for (int b2 = a + 1; b2 < m; ++b2, ++p) {
                int i = members[b + a], j = members[b + b2];
                pairList[p] = make_int2(min(i, j), max(i, j));
            }
    }
    __syncthreads();
    if (t == 0)  counters[1] = pairBase[NC];   // pairCount
}

// ---------------------------------------------------------------------------
// Node 2. 256 blocks: IoU per pair with fully-unrolled 15-iteration word loop
// (uniform via 960-word padded stride); block b owns consecutive pairs
// 8b..8b+7 which now share a class -> row reuse from L1/L2. Then vmcnt drain
// + done-ticket elects the last block for the LDS-reduce decay + final sort.
__global__ void __launch_bounds__(512)
k_ioudecay(const ull* __restrict__ packed, const int* __restrict__ order_g,
           const float* __restrict__ scoresS_g, const int* __restrict__ labelsS_g,
           const int2* __restrict__ pairList, int* __restrict__ counters,
           int* __restrict__ iouC, int* __restrict__ keepOrig_g,
           float* __restrict__ outScores, float* __restrict__ outLabels,
           float* __restrict__ outKeep) {
    const int t    = threadIdx.x;
    const int lane = t & 63;
    __shared__ int sLast;

    // ---- IoU stripes (wave per pair) ----
    int np = counters[1];              // node-1 data (dispatch boundary)
    for (int p = (int)blockIdx.x * 8 + (t >> 6); p < np; p += IOUB * 8) {
        int2 pr = pairList[p];
        const ull* A = packed + (size_t)order_g[pr.x] * NWP + lane;
        const ull* B = packed + (size_t)order_g[pr.y] * NWP + lane;
        ull acc = 0;  // inter | areaA<<21 | areaB<<42  (fields < 2^17)
#pragma unroll
        for (int k = 0; k < 15; ++k) {                   // uniform, unrolled
            ull a = A[k * 64], b = B[k * 64];
            acc += (ull)__popcll(a & b)
                 + ((ull)__popcll(a) << 21)
                 + ((ull)__popcll(b) << 42);
        }
#pragma unroll
        for (int off = 32; off > 0; off >>= 1) acc += __shfl_down(acc, off, 64);
        if (lane == 0) {
            float inter = (float)(int)(acc & 0x1FFFFF);
            float areaA = (float)(int)((acc >> 21) & 0x1FFFFF);
            float areaB = (float)(int)((acc >> 42) & 0x1FFFFF);
            float uni   = areaA + areaB - inter;    // exact small ints
            __hip_atomic_store(iouC + p, __float_as_int(inter / uni),
                               __ATOMIC_RELAXED, __HIP_MEMORY_SCOPE_AGENT);
        }
    }
    asm volatile("s_waitcnt vmcnt(0)" ::: "memory");   // stores at LLC
    __syncthreads();                                    // all waves drained
    if (t == 0) sLast = __hip_atomic_fetch_add(counters, 1, __ATOMIC_RELAXED,
                                               __HIP_MEMORY_SCOPE_AGENT);
    __syncthreads();
    if (sLast != IOUB - 1) return;

    // ---- decay (elected block): parallel stage + LDS-atomic reduce ----
    __shared__ int   labS[N];
    __shared__ int   compB[N];     // float bits of comp[j]  (init 0.0f)
    __shared__ int   coefB[N];     // float bits of coef[j]  (init 1.0f)
    __shared__ float sdec[N];
    __shared__ int2  pch[CHUNK];
    __shared__ float ich[CHUNK];

    if (t < N) {
        labS[t]  = labelsS_g[t];
        compB[t] = 0;              // 0.0f
        coefB[t] = 0x3F800000;     // 1.0f
    }
    __syncthreads();
    // pass 1: comp[j] = max over pairs (i,j) of iou   (exact, order-free)
    for (int base = 0; base < np; base += CHUNK) {
        int n = min(np - base, CHUNK);
        for (int u = t; u < n; u += 512) {
            pch[u] = pairList[base + u];
            ich[u] = __int_as_float(__hip_atomic_load(
                iouC + base + u, __ATOMIC_RELAXED, __HIP_MEMORY_SCOPE_AGENT));
        }
        __syncthreads();
        for (int u = t; u < n; u += 512)
            atomicMax(&compB[pch[u].y], __float_as_int(ich[u]));
        __syncthreads();
    }
    // pass 2: coef[j] = min over pairs (i,j) of exp(-2d^2)/exp(-2 comp[i]^2)
    for (int base = 0; base < np; base += CHUNK) {
        int n = min(np - base, CHUNK);
        for (int u = t; u < n; u += 512) {
            pch[u] = pairList[base + u];
            ich[u] = __int_as_float(__hip_atomic_load(
                iouC + base + u, __ATOMIC_RELAXED, __HIP_MEMORY_SCOPE_AGENT));
        }
        __syncthreads();
        for (int u = t; u < n; u += 512) {
            float d  = ich[u];
            float ci = __int_as_float(compB[pch[u].x]);
            float r  = expf(-2.f * d * d) / expf(-2.f * ci * ci);  // mirror np
            atomicMin(&coefB[pch[u].y], __float_as_int(r));
        }
        __syncthreads();
    }
    if (t < N) sdec[t] = scoresS_g[t] * __int_as_float(coefB[t]);
    __syncthreads();
    if (t < N) {                        // stable descending rank on decayed scores
        float sj = sdec[t];
        int rank = 0;
        for (int i = 0; i < N; ++i) {
            float si = sdec[i];
            if (si > sj || (si == sj && i < t)) rank++;
        }
        int o = order_g[t];
        outScores[rank]  = sj;
        outLabels[rank]  = (float)labS[t];
        outKeep[rank]    = (float)o;
        keepOrig_g[rank] = o;
    }
}

// ---------------------------------------------------------------------------
// Node 3. Expand kept masks to float output. 2D grid (R9-proven best);
// plain coalesced f32x4 stores; padded row stride.
__global__ void k_gather(const ull* __restrict__ packed, const int* __restrict__ keepOrig,
                         f32x4* __restrict__ outMasks) {
    int q = blockIdx.x * blockDim.x + threadIdx.x;   // quad within instance
    if (q >= HW / 4) return;
    int k    = blockIdx.y;
    int orig = keepOrig[k];                          // uniform -> scalar load
    ull w  = packed[(size_t)orig * NWP + (q >> 4)];  // pix = q*4; word = pix>>6
    int sh = (q & 15) * 4;
    f32x4 r;
    r.x = (float)((w >> (sh    )) & 1ULL);
    r.y = (float)((w >> (sh + 1)) & 1ULL);
    r.z = (float)((w >> (sh + 2)) & 1ULL);
    r.w = (float)((w >> (sh + 3)) & 1ULL);
    outMasks[(size_t)k * (HW / 4) + q] = r;
}

// ---------------------------------------------------------------------------
extern "C" void kernel_launch(void* const* d_in, const int* in_sizes, int n_in,
                              void* d_out, int out_size, void* d_ws, size_t ws_size,
                              hipStream_t stream) {
    const float* mask_preds = (const float*)d_in[0];
    const int*   labels     = (const int*)d_in[1];
    const float* scores     = (const float*)d_in[2];

    float*  o         = (float*)d_out;
    float*  outScores = o;
    float*  outLabels = o + N;
    f32x4*  outMasks  = (f32x4*)(o + 2 * N);
    float*  outKeep   = o + 2 * N + (size_t)N * HW;

    // workspace carve-up (16B-aligned chunks; ~5.4 MB total)
    char* w = (char*)d_ws;
    ull*   packed     = (ull*)w;   w += (size_t)N * NWP * 8;           // 3,840,000
    int*   order_g    = (int*)w;   w += N * 4;
    float* scoresS_g  = (float*)w; w += N * 4;
    int*   labelsS_g  = (int*)w;   w += N * 4;
    int*   keepOrig_g = (int*)w;   w += N * 4;
    int*   counters   = (int*)w;   w += 128;   // done-ticket, pairCount
    int*   iouC       = (int*)w;   w += (size_t)(N * (N - 1) / 2) * 4; // 499,000
    int2*  pairList   = (int2*)w;  /* N*(N-1)/2 * 8 = 998,000 */

    hipLaunchKernelGGL(k_packsort, dim3(PB + 1), dim3(512), 0, stream,
                       mask_preds, labels, scores, packed, order_g,
                       scoresS_g, labelsS_g, pairList, counters);
    hipLaunchKernelGGL(k_ioudecay, dim3(IOUB), dim3(512), 0, stream,
                       packed, order_g, scoresS_g, labelsS_g,
                       pairList, counters, iouC, keepOrig_g,
                       outScores, outLabels, outKeep);
    hipLaunchKernelGGL(k_gather, dim3(QPB, N), dim3(256), 0, stream,
                       packed, keepOrig_g, outMasks);
}